// Round 2
// baseline (2853.328 us; speedup 1.0000x reference)
//
#include <hip/hip_runtime.h>
#include <math.h>
#include <stddef.h>

#define NLAYER 24
#define NEMBD  1024
#define NFFN   4096
#define NB     256
#define NT     256
#define NW     4
#define LN_EPS 1e-5f

#define OUT_SA (NEMBD)
#define OUT_SB (NEMBD + NLAYER*NEMBD)
#define OUT_SC (NEMBD + 2*NLAYER*NEMBD)
#define OUT_SD (NEMBD + 3*NLAYER*NEMBD)

#define FLAG_STRIDE 32   // 32 u32 = 128 B per block flag line

struct Params {
  const float *x, *state, *ln1w, *ln1b, *ln2w, *ln2b, *td, *tf, *kktk, *vvtv, *rrtr;
  const float *key, *outputv, *tmk, *tmr, *kffn, *rffn, *vffn;
  float *out;
  float *xbuf, *kvr, *sxx, *rfb, *kfb;
  unsigned *flags, *gen;
};

__device__ __forceinline__ float wred(float v) {
#pragma unroll
  for (int o = 32; o > 0; o >>= 1) v += __shfl_xor(v, o, 64);
  return v;
}

__device__ __forceinline__ float dot4(float4 a, float4 b) {
  return a.x*b.x + a.y*b.y + a.z*b.z + a.w*b.w;
}

// ---- two-hop flag barrier: no atomic RMW, no shared-line contention ----
// arrive: block's work drained (__syncthreads implies vmcnt(0)), thread0
// publishes flag[b]=tgt with release semantics (writes back XCD L2).
__device__ __forceinline__ void bar_arrive(unsigned* flags, unsigned tgt) {
  __syncthreads();
  if (threadIdx.x == 0) {
    __threadfence();
    __hip_atomic_store(&flags[(unsigned)blockIdx.x * FLAG_STRIDE], tgt,
                       __ATOMIC_RELEASE, __HIP_MEMORY_SCOPE_AGENT);
  }
}

// wait: block0's thread t polls flag[t]; once all present, block0 publishes
// gen=tgt; other blocks poll gen. threadfence after observation = acquire
// (invalidates L1/L2 so ws reads see remote writes).
__device__ __forceinline__ void bar_wait(unsigned* flags, unsigned* gen, unsigned tgt) {
  if (blockIdx.x == 0) {
    long spin = 0;
    while (__hip_atomic_load(&flags[(unsigned)threadIdx.x * FLAG_STRIDE],
                             __ATOMIC_RELAXED, __HIP_MEMORY_SCOPE_AGENT) < tgt) {
      __builtin_amdgcn_s_sleep(1);
      if (++spin > (1L << 24)) break;   // safety valve
    }
    __syncthreads();
    if (threadIdx.x == 0) {
      __threadfence();
      __hip_atomic_store(gen, tgt, __ATOMIC_RELEASE, __HIP_MEMORY_SCOPE_AGENT);
    }
  } else if (threadIdx.x == 0) {
    long spin = 0;
    while (__hip_atomic_load(gen, __ATOMIC_RELAXED, __HIP_MEMORY_SCOPE_AGENT) < tgt) {
      __builtin_amdgcn_s_sleep(1);
      if (++spin > (1L << 24)) break;
    }
    __threadfence();
  }
  __syncthreads();
}

__global__ void __launch_bounds__(NT, 1)
rwkv_persistent(Params p) {
  const int b    = blockIdx.x;
  const int t    = threadIdx.x;
  const int wid  = t >> 6;
  const int lane = t & 63;

  __shared__ float lds[NFFN];
  __shared__ float reda[NW], redq[NW];
  __shared__ float mrs[2];

  float4 wr[20];                 // cross-barrier weight prefetch registers
  unsigned g = 1;

  // ---- stage -1: stage x into ws ----
  if (b == 0) {
    *(float4*)&p.xbuf[t * 4] = *(const float4*)&p.x[t * 4];
  }
  bar_arrive(p.flags, g);
  { // prefetch stage-1 weights, layer 0 (overlaps barrier wait)
    const float* W = p.key + (size_t)(b * 12 + wid * 3) * NEMBD + lane * 4;
#pragma unroll
    for (int r = 0; r < 3; ++r)
#pragma unroll
      for (int jj = 0; jj < 4; ++jj)
        wr[r * 4 + jj] = *(const float4*)&W[(size_t)r * NEMBD + jj * 256];
  }
  bar_wait(p.flags, p.gen, g); ++g;

  for (int l = 0; l < NLAYER; ++l) {
    // ================= stage 1: ln1 + k/v/r GEMV =================
    {
      const int i0 = t * 4;
      float4 x4 = *(const float4*)&p.xbuf[i0];
      float xa[4] = {x4.x, x4.y, x4.z, x4.w};
      float s = xa[0] + xa[1] + xa[2] + xa[3];
      float q = xa[0]*xa[0] + xa[1]*xa[1] + xa[2]*xa[2] + xa[3]*xa[3];
      s = wred(s); q = wred(q);
      if (lane == 0) { reda[wid] = s; redq[wid] = q; }
      __syncthreads();
      if (t == 0) {
        float ts = 0.f, tq = 0.f;
#pragma unroll
        for (int i = 0; i < NW; ++i) { ts += reda[i]; tq += redq[i]; }
        float m = ts * (1.f / NEMBD);
        float var = tq * (1.f / NEMBD) - m * m;
        mrs[0] = m; mrs[1] = rsqrtf(var + LN_EPS);
      }
      __syncthreads();
      float m = mrs[0], rs = mrs[1];
      const float* l1w = p.ln1w + l * NEMBD;
      const float* l1b = p.ln1b + l * NEMBD;
      const float* sa  = p.state + 0 * NLAYER * NEMBD + l * NEMBD;
      const float* kkp = p.kktk + l * NEMBD;
      const float* vvp = p.vvtv + l * NEMBD;
      const float* rrp = p.rrtr + l * NEMBD;
#pragma unroll
      for (int j = 0; j < 4; ++j) {
        int i = i0 + j;
        float xy = (xa[j] - m) * rs * l1w[i] + l1b[i];
        float sav = sa[i];
        lds[i]             = xy + kkp[i] * sav;
        lds[NEMBD + i]     = xy + vvp[i] * sav;
        lds[2 * NEMBD + i] = xy + rrp[i] * sav;
        if (b == 0) p.out[OUT_SA + l * NEMBD + i] = xy;   // statea_new = xy
      }
      __syncthreads();

      const int r0 = b * 12 + wid * 3;   // 3072 rows over 1024 waves
      const float* v0 = lds + ((r0 + 0) >> 10) * NEMBD;
      const float* v1 = lds + ((r0 + 1) >> 10) * NEMBD;
      const float* v2 = lds + ((r0 + 2) >> 10) * NEMBD;
      float a0 = 0.f, a1 = 0.f, a2 = 0.f;
#pragma unroll
      for (int jj = 0; jj < 4; ++jj) {
        int col = lane * 4 + jj * 256;
        a0 += dot4(wr[0 * 4 + jj], *(const float4*)&v0[col]);
        a1 += dot4(wr[1 * 4 + jj], *(const float4*)&v1[col]);
        a2 += dot4(wr[2 * 4 + jj], *(const float4*)&v2[col]);
      }
      a0 = wred(a0); a1 = wred(a1); a2 = wred(a2);
      if (lane == 0) {
        p.kvr[r0 + 0] = a0;
        p.kvr[r0 + 1] = a1;
        p.kvr[r0 + 2] = a2;
      }
    }
    bar_arrive(p.flags, g);
    const int row2 = b * 4 + wid;
    { // prefetch stage-2 weights (outputv row)
      const float* W = p.outputv + ((size_t)l * NEMBD + row2) * NEMBD + lane * 4;
#pragma unroll
      for (int jj = 0; jj < 4; ++jj)
        wr[jj] = *(const float4*)&W[jj * 256];
    }
    bar_wait(p.flags, p.gen, g); ++g;

    // ================= stage 2: wkv combine + outputv GEMV + state out ====
    {
      const int i0 = t * 4;
      const float* tfp = p.tf + l * NEMBD;
      const float* sbp = p.state + 1 * NLAYER * NEMBD + l * NEMBD;
      const float* scp = p.state + 2 * NLAYER * NEMBD + l * NEMBD;
      const float* tdp = p.td + l * NEMBD;
#pragma unroll
      for (int j = 0; j < 4; ++j) {
        int i = i0 + j;
        float k = p.kvr[i];
        float v = p.kvr[NEMBD + i];
        float r = p.kvr[2 * NEMBD + i];
        float sb = sbp[i], sc = scp[i];
        float etfk = expf(tfp[i] + k);
        float er   = expf(r);
        lds[i] = (sb + etfk * v) / ((sc + etfk) * (1.f + er));
        if (b == 0) {
          float ek = expf(k), ed = expf(tdp[i]);
          p.out[OUT_SB + l * NEMBD + i] = sb * ed + ek * v;
          p.out[OUT_SC + l * NEMBD + i] = sc * ed + ek;
        }
      }
      __syncthreads();
      float acc = 0.f;
#pragma unroll
      for (int jj = 0; jj < 4; ++jj) {
        int col = lane * 4 + jj * 256;
        acc += dot4(wr[jj], *(const float4*)&lds[col]);
      }
      acc = wred(acc);
      if (lane == 0) p.sxx[row2] = p.xbuf[row2] + acc;
    }
    bar_arrive(p.flags, g);
    int isk3[5], rid3[5], voff3[5];
    { // prefetch stage-3 weights: 16 kffn rows + 4 rffn rows per block
#pragma unroll
      for (int sI = 0; sI < 5; ++sI) {
        int qI = wid * 5 + sI;
        const float* wp;
        if (qI < 16) {
          int row = b * 16 + qI;
          wp = p.kffn + ((size_t)l * NFFN + row) * NEMBD;
          isk3[sI] = 1; rid3[sI] = row; voff3[sI] = 0;
        } else {
          int row = b * 4 + (qI - 16);
          wp = p.rffn + ((size_t)l * NEMBD + row) * NEMBD;
          isk3[sI] = 0; rid3[sI] = row; voff3[sI] = NEMBD;
        }
        wp += lane * 4;
#pragma unroll
        for (int jj = 0; jj < 4; ++jj)
          wr[sI * 4 + jj] = *(const float4*)&wp[jj * 256];
      }
    }
    bar_wait(p.flags, p.gen, g); ++g;

    // ================= stage 3: ln2 + key_ffn / receptance_ffn GEMV =======
    {
      const int i0 = t * 4;
      float4 s4 = *(const float4*)&p.sxx[i0];
      float xa[4] = {s4.x, s4.y, s4.z, s4.w};
      float s = xa[0] + xa[1] + xa[2] + xa[3];
      float q = xa[0]*xa[0] + xa[1]*xa[1] + xa[2]*xa[2] + xa[3]*xa[3];
      s = wred(s); q = wred(q);
      if (lane == 0) { reda[wid] = s; redq[wid] = q; }
      __syncthreads();
      if (t == 0) {
        float ts = 0.f, tq = 0.f;
#pragma unroll
        for (int i = 0; i < NW; ++i) { ts += reda[i]; tq += redq[i]; }
        float m = ts * (1.f / NEMBD);
        float var = tq * (1.f / NEMBD) - m * m;
        mrs[0] = m; mrs[1] = rsqrtf(var + LN_EPS);
      }
      __syncthreads();
      float m = mrs[0], rs = mrs[1];
      const float* l2w = p.ln2w + l * NEMBD;
      const float* l2b = p.ln2b + l * NEMBD;
      const float* sdp = p.state + 3 * NLAYER * NEMBD + l * NEMBD;
      const float* tmkp = p.tmk + l * NEMBD;
      const float* tmrp = p.tmr + l * NEMBD;
#pragma unroll
      for (int j = 0; j < 4; ++j) {
        int i = i0 + j;
        float xx = (xa[j] - m) * rs * l2w[i] + l2b[i];
        float sdv = sdp[i];
        lds[i]         = xx + tmkp[i] * sdv;
        lds[NEMBD + i] = xx + tmrp[i] * sdv;
        if (b == 0) p.out[OUT_SD + l * NEMBD + i] = xx;   // stated_new = xx
      }
      __syncthreads();

      float acc[5] = {0.f, 0.f, 0.f, 0.f, 0.f};
#pragma unroll
      for (int jj = 0; jj < 4; ++jj) {
        int col = lane * 4 + jj * 256;
#pragma unroll
        for (int sI = 0; sI < 5; ++sI)
          acc[sI] += dot4(wr[sI * 4 + jj], *(const float4*)&lds[voff3[sI] + col]);
      }
#pragma unroll
      for (int sI = 0; sI < 5; ++sI) {
        float r = wred(acc[sI]);
        if (lane == 0) {
          if (isk3[sI]) { float kv = fmaxf(r, 0.f); p.kfb[rid3[sI]] = kv * kv; }
          else          { p.rfb[rid3[sI]] = expf(r); }
        }
      }
    }
    bar_arrive(p.flags, g);
    const int row4 = b * 4 + wid;
    { // prefetch stage-4 weights (vffn row, 4096 wide)
      const float* W = p.vffn + ((size_t)l * NEMBD + row4) * NFFN + lane * 4;
#pragma unroll
      for (int jj = 0; jj < 16; ++jj)
        wr[jj] = *(const float4*)&W[jj * 256];
    }
    bar_wait(p.flags, p.gen, g); ++g;

    // ================= stage 4: value_ffn GEMV + x update =================
    {
#pragma unroll
      for (int pass = 0; pass < 4; ++pass) {
        int idx = pass * NEMBD + t * 4;
        *(float4*)&lds[idx] = *(const float4*)&p.kfb[idx];
      }
      __syncthreads();
      float accA = 0.f, accB = 0.f;
#pragma unroll
      for (int jj = 0; jj < 16; jj += 2) {
        int col = lane * 4 + jj * 256;
        accA += dot4(wr[jj],     *(const float4*)&lds[col]);
        accB += dot4(wr[jj + 1], *(const float4*)&lds[col + 256]);
      }
      float acc = wred(accA + accB);
      if (lane == 0) {
        float xn = p.sxx[row4] + acc / (p.rfb[row4] + 1.f);
        if (l == NLAYER - 1) p.out[row4] = xn;     // final x_out
        else                 p.xbuf[row4] = xn;
      }
    }
    bar_arrive(p.flags, g);
    if (l < NLAYER - 1) { // prefetch next layer's stage-1 weights
      const float* W = p.key + (size_t)(l + 1) * 3 * NEMBD * NEMBD
                     + (size_t)(b * 12 + wid * 3) * NEMBD + lane * 4;
#pragma unroll
      for (int r = 0; r < 3; ++r)
#pragma unroll
        for (int jj = 0; jj < 4; ++jj)
          wr[r * 4 + jj] = *(const float4*)&W[(size_t)r * NEMBD + jj * 256];
    }
    bar_wait(p.flags, p.gen, g); ++g;
  }
}

__global__ void rwkv_init(unsigned* flags, unsigned* gen) {
  flags[threadIdx.x * FLAG_STRIDE] = 0u;
  if (threadIdx.x == 0) *gen = 0u;
}

extern "C" void kernel_launch(void* const* d_in, const int* in_sizes, int n_in,
                              void* d_out, int out_size, void* d_ws, size_t ws_size,
                              hipStream_t stream) {
  Params p;
  p.x       = (const float*)d_in[0];
  p.state   = (const float*)d_in[1];
  p.ln1w    = (const float*)d_in[2];
  p.ln1b    = (const float*)d_in[3];
  p.ln2w    = (const float*)d_in[4];
  p.ln2b    = (const float*)d_in[5];
  p.td      = (const float*)d_in[6];
  p.tf      = (const float*)d_in[7];
  p.kktk    = (const float*)d_in[8];
  p.vvtv    = (const float*)d_in[9];
  p.rrtr    = (const float*)d_in[10];
  p.key     = (const float*)d_in[11];
  p.outputv = (const float*)d_in[12];
  p.tmk     = (const float*)d_in[13];
  p.tmr     = (const float*)d_in[14];
  p.kffn    = (const float*)d_in[15];
  p.rffn    = (const float*)d_in[16];
  p.vffn    = (const float*)d_in[17];
  p.out     = (float*)d_out;

  float* ws = (float*)d_ws;
  p.xbuf = ws;                       // [1024]
  p.kvr  = ws + NEMBD;               // [3*1024]
  p.sxx  = ws + 4 * NEMBD;           // [1024]
  p.rfb  = ws + 5 * NEMBD;           // [1024]
  p.kfb  = ws + 6 * NEMBD;           // [4096]   -> ends at byte 40960
  p.flags = (unsigned*)((char*)d_ws + 49152);   // 256 x 128B = 32 KiB
  p.gen   = (unsigned*)((char*)d_ws + 81920);

  rwkv_init<<<1, NB, 0, stream>>>(p.flags, p.gen);
  rwkv_persistent<<<NB, NT, 0, stream>>>(p);
}

// Round 3
// 534.827 us; speedup vs baseline: 5.3350x; 5.3350x over previous
//
#include <hip/hip_runtime.h>
#include <math.h>
#include <stddef.h>

#define NLAYER 24
#define NEMBD  1024
#define NFFN   4096
#define NB     256
#define NT     256
#define NW     4
#define LN_EPS 1e-5f

#define OUT_SA (NEMBD)
#define OUT_SB (NEMBD + NLAYER*NEMBD)
#define OUT_SC (NEMBD + 2*NLAYER*NEMBD)
#define OUT_SD (NEMBD + 3*NLAYER*NEMBD)

#define FLAG_STRIDE 32   // 32 u32 = 128 B per block flag line

struct Params {
  const float *x, *state, *ln1w, *ln1b, *ln2w, *ln2b, *td, *tf, *kktk, *vvtv, *rrtr;
  const float *key, *outputv, *tmk, *tmr, *kffn, *rffn, *vffn;
  float *out;
  float *xbuf, *kvr, *sxx, *rfb, *kfb;
  unsigned *flags;
};

__device__ __forceinline__ float wred(float v) {
#pragma unroll
  for (int o = 32; o > 0; o >>= 1) v += __shfl_xor(v, o, 64);
  return v;
}

__device__ __forceinline__ float dot4(float4 a, float4 b) {
  return a.x*b.x + a.y*b.y + a.z*b.z + a.w*b.w;
}

// Cross-block data ops: relaxed agent-scope atomics compile to sc0/sc1
// global ops that bypass the non-coherent XCD L2 and hit the LLC directly.
// No cache-wide fences (wbl2/inv) are needed anywhere.
__device__ __forceinline__ float gload(const float* a) {
  return __hip_atomic_load(a, __ATOMIC_RELAXED, __HIP_MEMORY_SCOPE_AGENT);
}
__device__ __forceinline__ void gstore(float* a, float v) {
  __hip_atomic_store(a, v, __ATOMIC_RELAXED, __HIP_MEMORY_SCOPE_AGENT);
}

// Single-hop all-to-all barrier. arrive: __syncthreads() drains this block's
// vmem (data sc-stores are then at the LLC), thread 0 publishes flag[b]=tgt.
// wait: thread t polls flag[t]; each block detects independently (no relay,
// so one block's prefetch drain delays only itself).
__device__ __forceinline__ void bar_arrive(unsigned* flags, unsigned tgt) {
  __syncthreads();
  asm volatile("" ::: "memory");
  if (threadIdx.x == 0) {
    __hip_atomic_store(&flags[(unsigned)blockIdx.x * FLAG_STRIDE], tgt,
                       __ATOMIC_RELAXED, __HIP_MEMORY_SCOPE_AGENT);
  }
  asm volatile("" ::: "memory");
}

__device__ __forceinline__ void bar_wait(unsigned* flags, unsigned tgt) {
  asm volatile("" ::: "memory");
  long spin = 0;
  while (__hip_atomic_load(&flags[(unsigned)threadIdx.x * FLAG_STRIDE],
                           __ATOMIC_RELAXED, __HIP_MEMORY_SCOPE_AGENT) < tgt) {
    __builtin_amdgcn_s_sleep(1);
    if (++spin > (1L << 18)) break;   // safety valve: wrong beats hang
  }
  asm volatile("" ::: "memory");
  __syncthreads();
}

__global__ void __launch_bounds__(NT, 1)
rwkv_persistent(Params p) {
  const int b    = blockIdx.x;
  const int t    = threadIdx.x;
  const int wid  = t >> 6;
  const int lane = t & 63;

  __shared__ float lds[NFFN];
  __shared__ float reda[NW], redq[NW];
  __shared__ float mrs[2];

  float4 wr[20];                 // cross-barrier weight prefetch registers
  unsigned g = 1;

  { // prefetch layer-0 stage-1 weights (no barrier needed before stage 1)
    const float* W = p.key + (size_t)(b * 12 + wid * 3) * NEMBD + lane * 4;
#pragma unroll
    for (int r = 0; r < 3; ++r)
#pragma unroll
      for (int jj = 0; jj < 4; ++jj)
        wr[r * 4 + jj] = *(const float4*)&W[(size_t)r * NEMBD + jj * 256];
  }

  for (int l = 0; l < NLAYER; ++l) {
    // ================= stage 1: ln1 + k/v/r GEMV =================
    {
      const int i0 = t * 4;
      float xa[4];
      if (l == 0) {
        float4 x4 = *(const float4*)&p.x[i0];
        xa[0] = x4.x; xa[1] = x4.y; xa[2] = x4.z; xa[3] = x4.w;
      } else {
#pragma unroll
        for (int j = 0; j < 4; ++j) xa[j] = gload(&p.xbuf[i0 + j]);
      }
      float s = xa[0] + xa[1] + xa[2] + xa[3];
      float q = xa[0]*xa[0] + xa[1]*xa[1] + xa[2]*xa[2] + xa[3]*xa[3];
      s = wred(s); q = wred(q);
      if (lane == 0) { reda[wid] = s; redq[wid] = q; }
      __syncthreads();
      if (t == 0) {
        float ts = 0.f, tq = 0.f;
#pragma unroll
        for (int i = 0; i < NW; ++i) { ts += reda[i]; tq += redq[i]; }
        float m = ts * (1.f / NEMBD);
        float var = tq * (1.f / NEMBD) - m * m;
        mrs[0] = m; mrs[1] = rsqrtf(var + LN_EPS);
      }
      __syncthreads();
      float m = mrs[0], rs = mrs[1];
      const float* l1w = p.ln1w + l * NEMBD;
      const float* l1b = p.ln1b + l * NEMBD;
      const float* sa  = p.state + 0 * NLAYER * NEMBD + l * NEMBD;
      const float* kkp = p.kktk + l * NEMBD;
      const float* vvp = p.vvtv + l * NEMBD;
      const float* rrp = p.rrtr + l * NEMBD;
#pragma unroll
      for (int j = 0; j < 4; ++j) {
        int i = i0 + j;
        float xy = (xa[j] - m) * rs * l1w[i] + l1b[i];
        float sav = sa[i];
        lds[i]             = xy + kkp[i] * sav;
        lds[NEMBD + i]     = xy + vvp[i] * sav;
        lds[2 * NEMBD + i] = xy + rrp[i] * sav;
        if (b == 0) p.out[OUT_SA + l * NEMBD + i] = xy;   // statea_new = xy
      }
      __syncthreads();

      const int r0 = b * 12 + wid * 3;   // 3072 rows over 1024 waves
      const float* v0 = lds + ((r0 + 0) >> 10) * NEMBD;
      const float* v1 = lds + ((r0 + 1) >> 10) * NEMBD;
      const float* v2 = lds + ((r0 + 2) >> 10) * NEMBD;
      float a0 = 0.f, a1 = 0.f, a2 = 0.f;
#pragma unroll
      for (int jj = 0; jj < 4; ++jj) {
        int col = lane * 4 + jj * 256;
        a0 += dot4(wr[0 * 4 + jj], *(const float4*)&v0[col]);
        a1 += dot4(wr[1 * 4 + jj], *(const float4*)&v1[col]);
        a2 += dot4(wr[2 * 4 + jj], *(const float4*)&v2[col]);
      }
      a0 = wred(a0); a1 = wred(a1); a2 = wred(a2);
      if (lane == 0) {
        gstore(&p.kvr[r0 + 0], a0);
        gstore(&p.kvr[r0 + 1], a1);
        gstore(&p.kvr[r0 + 2], a2);
      }
    }
    bar_arrive(p.flags, g);
    const int row2 = b * 4 + wid;
    { // prefetch stage-2 weights (outputv row) — overlaps barrier wait
      const float* W = p.outputv + ((size_t)l * NEMBD + row2) * NEMBD + lane * 4;
#pragma unroll
      for (int jj = 0; jj < 4; ++jj)
        wr[jj] = *(const float4*)&W[jj * 256];
    }
    bar_wait(p.flags, g); ++g;

    // ================= stage 2: wkv combine + outputv GEMV + state out ====
    {
      const int i0 = t * 4;
      const float* tfp = p.tf + l * NEMBD;
      const float* sbp = p.state + 1 * NLAYER * NEMBD + l * NEMBD;
      const float* scp = p.state + 2 * NLAYER * NEMBD + l * NEMBD;
      const float* tdp = p.td + l * NEMBD;
#pragma unroll
      for (int j = 0; j < 4; ++j) {
        int i = i0 + j;
        float k = gload(&p.kvr[i]);
        float v = gload(&p.kvr[NEMBD + i]);
        float r = gload(&p.kvr[2 * NEMBD + i]);
        float sb = sbp[i], sc = scp[i];
        float etfk = expf(tfp[i] + k);
        float er   = expf(r);
        // sc*er + exp(tf+k+r) + sc + etfk == (sc+etfk)*(1+er)
        lds[i] = (sb + etfk * v) / ((sc + etfk) * (1.f + er));
        if (b == 0) {
          float ek = expf(k), ed = expf(tdp[i]);
          p.out[OUT_SB + l * NEMBD + i] = sb * ed + ek * v;
          p.out[OUT_SC + l * NEMBD + i] = sc * ed + ek;
        }
      }
      __syncthreads();
      float acc = 0.f;
#pragma unroll
      for (int jj = 0; jj < 4; ++jj) {
        int col = lane * 4 + jj * 256;
        acc += dot4(wr[jj], *(const float4*)&lds[col]);
      }
      acc = wred(acc);
      if (lane == 0) {
        float xc = (l == 0) ? p.x[row2] : gload(&p.xbuf[row2]);
        gstore(&p.sxx[row2], xc + acc);
      }
    }
    bar_arrive(p.flags, g);
    int isk3[5], rid3[5], voff3[5];
    { // prefetch stage-3 weights: 16 kffn rows + 4 rffn rows per block
#pragma unroll
      for (int sI = 0; sI < 5; ++sI) {
        int qI = wid * 5 + sI;
        const float* wp;
        if (qI < 16) {
          int row = b * 16 + qI;
          wp = p.kffn + ((size_t)l * NFFN + row) * NEMBD;
          isk3[sI] = 1; rid3[sI] = row; voff3[sI] = 0;
        } else {
          int row = b * 4 + (qI - 16);
          wp = p.rffn + ((size_t)l * NEMBD + row) * NEMBD;
          isk3[sI] = 0; rid3[sI] = row; voff3[sI] = NEMBD;
        }
        wp += lane * 4;
#pragma unroll
        for (int jj = 0; jj < 4; ++jj)
          wr[sI * 4 + jj] = *(const float4*)&wp[jj * 256];
      }
    }
    bar_wait(p.flags, g); ++g;

    // ================= stage 3: ln2 + key_ffn / receptance_ffn GEMV =======
    {
      const int i0 = t * 4;
      float xa[4];
#pragma unroll
      for (int j = 0; j < 4; ++j) xa[j] = gload(&p.sxx[i0 + j]);
      float s = xa[0] + xa[1] + xa[2] + xa[3];
      float q = xa[0]*xa[0] + xa[1]*xa[1] + xa[2]*xa[2] + xa[3]*xa[3];
      s = wred(s); q = wred(q);
      if (lane == 0) { reda[wid] = s; redq[wid] = q; }
      __syncthreads();
      if (t == 0) {
        float ts = 0.f, tq = 0.f;
#pragma unroll
        for (int i = 0; i < NW; ++i) { ts += reda[i]; tq += redq[i]; }
        float m = ts * (1.f / NEMBD);
        float var = tq * (1.f / NEMBD) - m * m;
        mrs[0] = m; mrs[1] = rsqrtf(var + LN_EPS);
      }
      __syncthreads();
      float m = mrs[0], rs = mrs[1];
      const float* l2w = p.ln2w + l * NEMBD;
      const float* l2b = p.ln2b + l * NEMBD;
      const float* sdp = p.state + 3 * NLAYER * NEMBD + l * NEMBD;
      const float* tmkp = p.tmk + l * NEMBD;
      const float* tmrp = p.tmr + l * NEMBD;
#pragma unroll
      for (int j = 0; j < 4; ++j) {
        int i = i0 + j;
        float xx = (xa[j] - m) * rs * l2w[i] + l2b[i];
        float sdv = sdp[i];
        lds[i]         = xx + tmkp[i] * sdv;
        lds[NEMBD + i] = xx + tmrp[i] * sdv;
        if (b == 0) p.out[OUT_SD + l * NEMBD + i] = xx;   // stated_new = xx
      }
      __syncthreads();

      float acc[5] = {0.f, 0.f, 0.f, 0.f, 0.f};
#pragma unroll
      for (int jj = 0; jj < 4; ++jj) {
        int col = lane * 4 + jj * 256;
#pragma unroll
        for (int sI = 0; sI < 5; ++sI)
          acc[sI] += dot4(wr[sI * 4 + jj], *(const float4*)&lds[voff3[sI] + col]);
      }
#pragma unroll
      for (int sI = 0; sI < 5; ++sI) {
        float r = wred(acc[sI]);
        if (lane == 0) {
          if (isk3[sI]) { float kv = fmaxf(r, 0.f); gstore(&p.kfb[rid3[sI]], kv * kv); }
          else          { gstore(&p.rfb[rid3[sI]], expf(r)); }
        }
      }
    }
    bar_arrive(p.flags, g);
    const int row4 = b * 4 + wid;
    { // prefetch stage-4 weights (vffn row, 4096 wide)
      const float* W = p.vffn + ((size_t)l * NEMBD + row4) * NFFN + lane * 4;
#pragma unroll
      for (int jj = 0; jj < 16; ++jj)
        wr[jj] = *(const float4*)&W[jj * 256];
    }
    bar_wait(p.flags, g); ++g;

    // ================= stage 4: value_ffn GEMV + x update =================
    {
#pragma unroll
      for (int pass = 0; pass < 4; ++pass) {
        int idx = pass * NEMBD + t * 4;
        float a0 = gload(&p.kfb[idx + 0]);
        float a1 = gload(&p.kfb[idx + 1]);
        float a2 = gload(&p.kfb[idx + 2]);
        float a3 = gload(&p.kfb[idx + 3]);
        *(float4*)&lds[idx] = make_float4(a0, a1, a2, a3);
      }
      __syncthreads();
      float accA = 0.f, accB = 0.f;
#pragma unroll
      for (int jj = 0; jj < 16; jj += 2) {
        int col = lane * 4 + jj * 256;
        accA += dot4(wr[jj],     *(const float4*)&lds[col]);
        accB += dot4(wr[jj + 1], *(const float4*)&lds[col + 256]);
      }
      float acc = wred(accA + accB);
      if (lane == 0) {
        float xn = gload(&p.sxx[row4]) + acc / (gload(&p.rfb[row4]) + 1.f);
        if (l == NLAYER - 1) p.out[row4] = xn;     // final x_out
        else                 gstore(&p.xbuf[row4], xn);
      }
    }
    bar_arrive(p.flags, g);
    if (l < NLAYER - 1) { // prefetch next layer's stage-1 weights
      const float* W = p.key + (size_t)(l + 1) * 3 * NEMBD * NEMBD
                     + (size_t)(b * 12 + wid * 3) * NEMBD + lane * 4;
#pragma unroll
      for (int r = 0; r < 3; ++r)
#pragma unroll
        for (int jj = 0; jj < 4; ++jj)
          wr[r * 4 + jj] = *(const float4*)&W[(size_t)r * NEMBD + jj * 256];
    }
    bar_wait(p.flags, g); ++g;
  }
}

__global__ void rwkv_init(unsigned* flags) {
  flags[threadIdx.x * FLAG_STRIDE] = 0u;
}

extern "C" void kernel_launch(void* const* d_in, const int* in_sizes, int n_in,
                              void* d_out, int out_size, void* d_ws, size_t ws_size,
                              hipStream_t stream) {
  Params p;
  p.x       = (const float*)d_in[0];
  p.state   = (const float*)d_in[1];
  p.ln1w    = (const float*)d_in[2];
  p.ln1b    = (const float*)d_in[3];
  p.ln2w    = (const float*)d_in[4];
  p.ln2b    = (const float*)d_in[5];
  p.td      = (const float*)d_in[6];
  p.tf      = (const float*)d_in[7];
  p.kktk    = (const float*)d_in[8];
  p.vvtv    = (const float*)d_in[9];
  p.rrtr    = (const float*)d_in[10];
  p.key     = (const float*)d_in[11];
  p.outputv = (const float*)d_in[12];
  p.tmk     = (const float*)d_in[13];
  p.tmr     = (const float*)d_in[14];
  p.kffn    = (const float*)d_in[15];
  p.rffn    = (const float*)d_in[16];
  p.vffn    = (const float*)d_in[17];
  p.out     = (float*)d_out;

  float* ws = (float*)d_ws;
  p.xbuf = ws;                       // [1024]
  p.kvr  = ws + NEMBD;               // [3*1024]
  p.sxx  = ws + 4 * NEMBD;           // [1024]
  p.rfb  = ws + 5 * NEMBD;           // [1024]
  p.kfb  = ws + 6 * NEMBD;           // [4096]   -> ends at byte 40960
  p.flags = (unsigned*)((char*)d_ws + 49152);   // 256 x 128B = 32 KiB

  rwkv_init<<<1, NB, 0, stream>>>(p.flags);
  rwkv_persistent<<<NB, NT, 0, stream>>>(p);
}